// Round 1
// 541.181 us; speedup vs baseline: 1.0297x; 1.0297x over previous
//
#include <hip/hip_runtime.h>
#include <math.h>

#define NN 100000
#define NE 3200000
#define INF_ 256
#define NH 8
#define OF 64
#define EF 64
#define NT 8

#define BSH 7                  // log2(nodes per bucket)
#define BNODES 128             // nodes per bucket
#define NB 782                 // ceil(NN/128)
#define CAPB 4608              // slots/bucket: Poisson(4096)+8 sigma
#define SPLIT 4                // sub-blocks per bucket in k_bucket_sum
#define CHUNK 1152             // CAPB/SPLIT
#define EPB 4096               // edges per k_partition block

// ws layout (float units). el separated from ers so the 3.2MB el table fits per-XCD L2;
// ers[n] = {er[0..7], s[0..7]} shares one 64B line (K4 gathers er+s in ONE line).
// s-columns are zeroed by k_node and accumulated by k_bucket_sum via global atomicAdd
// (no partial buffer, no k_reduce).
static constexpr size_t WS_AT      = 0;                        // 4096
static constexpr size_t WS_EE      = 4096;                     // 64
static constexpr size_t WS_EL      = 4160;                     // NN*8
static constexpr size_t WS_ERS     = WS_EL + (size_t)NN * 8;   // NN*16 (64B-aligned: 804160%16==0)
static constexpr size_t WS_CCNT    = WS_ERS + (size_t)NN * 16; // NB
static constexpr size_t WS_PART    = WS_CCNT + NB + 2;         // NB*CAPB u32

// K1a: At[c][i] = sum_o W_fc[i, h*64+o]*attn[h,o]; c<8->attn_l, c>=8->attn_r. Zeroes ccnt.
__global__ __launch_bounds__(256) void k_prep_A(const float* __restrict__ W_fc,
                                                const float* __restrict__ attn_l,
                                                const float* __restrict__ attn_r,
                                                float* __restrict__ At,
                                                unsigned* __restrict__ ccnt) {
    int t = blockIdx.x * 256 + threadIdx.x;   // 0..4095
    if (t < NB) ccnt[t] = 0u;
    int c = t >> 8;
    int i = t & 255;
    int h = c & 7;
    const float* attn = (c < 8) ? attn_l : attn_r;
    const float* wrow = W_fc + (size_t)i * (NH * OF) + h * OF;
    const float* arow = attn + h * OF;
    float acc = 0.f;
#pragma unroll 8
    for (int o = 0; o < OF; ++o) acc += wrow[o] * arow[o];
    At[c * INF_ + i] = acc;
}

// K1b: ee_tab[t][h]
__global__ __launch_bounds__(512) void k_prep_ee(const float* __restrict__ edge_emb,
                                                 const float* __restrict__ W_e,
                                                 const float* __restrict__ attn_e,
                                                 float* __restrict__ ee_tab) {
    __shared__ float B[EF][NH];
    int t = threadIdx.x;
    int g = t >> 3, h = t & 7;
    const float* wrow = W_e + (size_t)g * (NH * EF) + h * EF;
    const float* arow = attn_e + h * EF;
    float acc = 0.f;
#pragma unroll 8
    for (int f = 0; f < EF; ++f) acc += wrow[f] * arow[f];
    B[g][h] = acc;
    __syncthreads();
    if (t < NT * NH) {
        int tt = t >> 3, hh = t & 7;
        float a = 0.f;
#pragma unroll 8
        for (int g2 = 0; g2 < EF; ++g2) a += edge_emb[tt * EF + g2] * B[g2][hh];
        ee_tab[tt * NH + hh] = a;
    }
}

// K2: el[n][h], ers[n][0..7]=er, ers[n][8..15]=0 (s accumulator init)
__global__ __launch_bounds__(256) void k_node(const float* __restrict__ feat,
                                              const float* __restrict__ At,
                                              float* __restrict__ el,
                                              float* __restrict__ ers) {
    int n = blockIdx.x * 256 + threadIdx.x;
    if (n >= NN) return;
    const float4* f4 = (const float4*)(feat + (size_t)n * INF_);
    const float4* A4 = (const float4*)At;
    float acc[16];
#pragma unroll
    for (int c = 0; c < 16; ++c) acc[c] = 0.f;
    for (int iq = 0; iq < INF_ / 4; ++iq) {
        float4 f = f4[iq];
#pragma unroll
        for (int c = 0; c < 16; ++c) {
            float4 a = A4[c * 64 + iq];
            acc[c] += f.x * a.x + f.y * a.y + f.z * a.z + f.w * a.w;
        }
    }
    float4* e4 = (float4*)(el + (size_t)n * 8);
    e4[0] = make_float4(acc[0], acc[1], acc[2], acc[3]);
    e4[1] = make_float4(acc[4], acc[5], acc[6], acc[7]);
    float4* r4 = (float4*)(ers + (size_t)n * 16);
    r4[0] = make_float4(acc[8], acc[9], acc[10], acc[11]);
    r4[1] = make_float4(acc[12], acc[13], acc[14], acc[15]);
    r4[2] = make_float4(0.f, 0.f, 0.f, 0.f);
    r4[3] = make_float4(0.f, 0.f, 0.f, 0.f);
}

// K3a: partition into NB buckets. recs cached in VGPRs (src/dst/etype read once).
__global__ __launch_bounds__(256) void k_partition(const int* __restrict__ src,
                                                   const int* __restrict__ dst,
                                                   const int* __restrict__ etype,
                                                   unsigned* __restrict__ ccnt,
                                                   unsigned* __restrict__ part) {
    __shared__ unsigned hist[NB];
    __shared__ unsigned cursor[NB];
    int tid = threadIdx.x;
    size_t base = (size_t)blockIdx.x * EPB;
    unsigned long long rc[16];
    for (int i = tid; i < NB; i += 256) hist[i] = 0u;
    __syncthreads();
#pragma unroll
    for (int k = 0; k < 16; ++k) {
        size_t j = base + (size_t)k * 256 + tid;
        if (j < NE) {
            int dj = dst[j];
            rc[k] = (unsigned long long)(unsigned)src[j]
                  | ((unsigned long long)(unsigned)etype[j] << 17)
                  | ((unsigned long long)(unsigned)dj << 20);
            atomicAdd(&hist[dj >> BSH], 1u);
        } else rc[k] = ~0ull;
    }
    __syncthreads();
    for (int i = tid; i < NB; i += 256) {
        unsigned h = hist[i];
        cursor[i] = h ? atomicAdd(ccnt + i, h) : 0u;
    }
    __syncthreads();
#pragma unroll
    for (int k = 0; k < 16; ++k) {
        if (rc[k] == ~0ull) continue;
        int dj = (int)(rc[k] >> 20);
        int b = dj >> BSH;
        unsigned pos = atomicAdd(&cursor[b], 1u);
        if (pos < CAPB)
            part[(size_t)b * CAPB + pos] =
                (unsigned)(rc[k] & 0xFFFFFull) | ((unsigned)(dj & (BNODES - 1)) << 20);
    }
}

// K3b: per-sub-bucket sum. lane=(edge_sub,head). Main loop is batched 4-wide:
// 4 part loads issued, then 4 el gathers, then 4 compute+LDS-atomic — amortizes the
// ~400-cycle L2 latency chain over 4 edges. Block epilogue atomically folds sbin
// into ers cols 8..15 (replaces the partial buffer + k_reduce kernel).
__global__ __launch_bounds__(256) void k_bucket_sum(const unsigned* __restrict__ part,
                                                    const unsigned* __restrict__ ccnt,
                                                    const float* __restrict__ el,
                                                    const float* __restrict__ ers,
                                                    const float* __restrict__ ee_tab,
                                                    float* __restrict__ ers_out) {
    __shared__ float sbin[BNODES * 9];
    __shared__ float er_l[BNODES * 9];
    __shared__ float ee_l[NT * NH];
    int bs = blockIdx.x;
    int b = bs >> 2, c = bs & 3;     // SPLIT=4
    int tid = threadIdx.x;
    int e_sub = tid >> 3, h = tid & 7;
    int n0 = b << BSH;
    int nn = NN - n0; if (nn > BNODES) nn = BNODES;

    for (int i = tid; i < BNODES * 9; i += 256) sbin[i] = 0.f;
    if (tid < NT * NH) ee_l[tid] = ee_tab[tid];
    for (int i = tid; i < nn * NH; i += 256) {
        int nl = i >> 3, hh = i & 7;
        er_l[nl * 9 + hh] = ers[(size_t)(n0 + nl) * 16 + hh];
    }
    __syncthreads();

    unsigned cnt = ccnt[b]; if (cnt > CAPB) cnt = CAPB;
    unsigned lo = (unsigned)c * CHUNK;
    unsigned hi = lo + CHUNK; if (hi > cnt) hi = cnt;
    const unsigned* pp = part + (size_t)b * CAPB;
    unsigned e = lo + (unsigned)e_sub;
    // main loop: 4 edges per lane per iteration
    for (; e + 96 < hi; e += 128) {
        unsigned r0 = pp[e];
        unsigned r1 = pp[e + 32];
        unsigned r2 = pp[e + 64];
        unsigned r3 = pp[e + 96];
        float l0 = el[(size_t)(r0 & 0x1FFFFu) * 8 + h];
        float l1 = el[(size_t)(r1 & 0x1FFFFu) * 8 + h];
        float l2 = el[(size_t)(r2 & 0x1FFFFu) * 8 + h];
        float l3 = el[(size_t)(r3 & 0x1FFFFu) * 8 + h];
        {
            int et = (int)((r0 >> 17) & 7u), dl = (int)((r0 >> 20) & (BNODES - 1));
            float v = l0 + er_l[dl * 9 + h] + ee_l[et * NH + h];
            atomicAdd(&sbin[dl * 9 + h], expf(fmaxf(v, 0.f)));
        }
        {
            int et = (int)((r1 >> 17) & 7u), dl = (int)((r1 >> 20) & (BNODES - 1));
            float v = l1 + er_l[dl * 9 + h] + ee_l[et * NH + h];
            atomicAdd(&sbin[dl * 9 + h], expf(fmaxf(v, 0.f)));
        }
        {
            int et = (int)((r2 >> 17) & 7u), dl = (int)((r2 >> 20) & (BNODES - 1));
            float v = l2 + er_l[dl * 9 + h] + ee_l[et * NH + h];
            atomicAdd(&sbin[dl * 9 + h], expf(fmaxf(v, 0.f)));
        }
        {
            int et = (int)((r3 >> 17) & 7u), dl = (int)((r3 >> 20) & (BNODES - 1));
            float v = l3 + er_l[dl * 9 + h] + ee_l[et * NH + h];
            atomicAdd(&sbin[dl * 9 + h], expf(fmaxf(v, 0.f)));
        }
    }
    // tail
    for (; e < hi; e += 32) {
        unsigned rec = pp[e];
        int sj = (int)(rec & 0x1FFFFu);
        int et = (int)((rec >> 17) & 7u);
        int dl = (int)((rec >> 20) & (BNODES - 1));
        float v = el[(size_t)sj * 8 + h] + er_l[dl * 9 + h] + ee_l[et * NH + h];
        atomicAdd(&sbin[dl * 9 + h], expf(fmaxf(v, 0.f)));
    }
    __syncthreads();
    for (int i = tid; i < nn * NH; i += 256) {
        int nl = i >> 3, hh = i & 7;
        atomicAdd(&ers_out[(size_t)(n0 + nl) * 16 + 8 + hh], sbin[nl * 9 + hh]);
    }
}

// K4: out[j][h] = exp(e)/s. Gathers exactly 2 lines/edge: el[sj] (32B in 3.2MB table),
// ers[dj] (er+s in one 64B line).
__global__ __launch_bounds__(256) void k_edge_out(const int* __restrict__ src,
                                                  const int* __restrict__ dst,
                                                  const int* __restrict__ etype,
                                                  const float* __restrict__ el,
                                                  const float* __restrict__ ers,
                                                  const float* __restrict__ ee_tab,
                                                  float* __restrict__ out) {
    int j = blockIdx.x * 256 + threadIdx.x;
    if (j >= NE) return;
    int sj = src[j], dj = dst[j], tj = etype[j];
    const float4* el4 = (const float4*)(el + (size_t)sj * 8);
    const float4* E   = (const float4*)(ers + (size_t)dj * 16);
    const float4* ee4 = (const float4*)(ee_tab + tj * NH);
    float4 l0 = el4[0], l1 = el4[1];
    float4 r0 = E[0], r1 = E[1];
    float4 s0 = E[2], s1 = E[3];
    float4 e0 = ee4[0], e1 = ee4[1];
    float4 o0, o1;
    o0.x = expf(fmaxf(l0.x + r0.x + e0.x, 0.f)) / s0.x;
    o0.y = expf(fmaxf(l0.y + r0.y + e0.y, 0.f)) / s0.y;
    o0.z = expf(fmaxf(l0.z + r0.z + e0.z, 0.f)) / s0.z;
    o0.w = expf(fmaxf(l0.w + r0.w + e0.w, 0.f)) / s0.w;
    o1.x = expf(fmaxf(l1.x + r1.x + e1.x, 0.f)) / s1.x;
    o1.y = expf(fmaxf(l1.y + r1.y + e1.y, 0.f)) / s1.y;
    o1.z = expf(fmaxf(l1.z + r1.z + e1.z, 0.f)) / s1.z;
    o1.w = expf(fmaxf(l1.w + r1.w + e1.w, 0.f)) / s1.w;
    float4* o4 = (float4*)(out + (size_t)j * NH);
    o4[0] = o0;
    o4[1] = o1;
}

extern "C" void kernel_launch(void* const* d_in, const int* in_sizes, int n_in,
                              void* d_out, int out_size, void* d_ws, size_t ws_size,
                              hipStream_t stream) {
    const float* feat     = (const float*)d_in[0];
    const int*   etype    = (const int*)d_in[1];
    const int*   src      = (const int*)d_in[2];
    const int*   dst      = (const int*)d_in[3];
    const float* W_fc     = (const float*)d_in[4];
    const float* edge_emb = (const float*)d_in[5];
    const float* W_e      = (const float*)d_in[6];
    const float* attn_l   = (const float*)d_in[7];
    const float* attn_r   = (const float*)d_in[8];
    const float* attn_e   = (const float*)d_in[9];

    float*    ws      = (float*)d_ws;
    float*    At      = ws + WS_AT;
    float*    ee_tab  = ws + WS_EE;
    float*    el      = ws + WS_EL;
    float*    ers     = ws + WS_ERS;
    unsigned* ccnt    = (unsigned*)(ws + WS_CCNT);
    unsigned* part    = (unsigned*)(ws + WS_PART);
    float*    out     = (float*)d_out;

    hipLaunchKernelGGL(k_prep_A, dim3(16), dim3(256), 0, stream, W_fc, attn_l, attn_r, At, ccnt);
    hipLaunchKernelGGL(k_prep_ee, dim3(1), dim3(512), 0, stream, edge_emb, W_e, attn_e, ee_tab);
    hipLaunchKernelGGL(k_node, dim3((NN + 255) / 256), dim3(256), 0, stream, feat, At, el, ers);
    hipLaunchKernelGGL(k_partition, dim3((NE + EPB - 1) / EPB), dim3(256), 0, stream,
                       src, dst, etype, ccnt, part);
    hipLaunchKernelGGL(k_bucket_sum, dim3(NB * SPLIT), dim3(256), 0, stream,
                       part, ccnt, el, ers, ee_tab, ers);
    hipLaunchKernelGGL(k_edge_out, dim3((NE + 255) / 256), dim3(256), 0, stream,
                       src, dst, etype, el, ers, ee_tab, out);
}

// Round 3
// 523.939 us; speedup vs baseline: 1.0636x; 1.0329x over previous
//
#include <hip/hip_runtime.h>
#include <math.h>

#define NN 100000
#define NE 3200000
#define INF_ 256
#define NH 8
#define OF 64
#define EF 64
#define NT 8

#define BSH 7                  // log2(nodes per bucket)
#define BNODES 128             // nodes per bucket
#define NB 782                 // ceil(NN/128)
#define CAPB 4608              // slots/bucket: Poisson(4096)+8 sigma
#define SPLIT 4                // sub-blocks per bucket in k_bucket_sum
#define EPB 4096               // edges per k_partition block

// ws layout (float units). el separated from ers so the 3.2MB el table fits per-XCD L2;
// ers[n] = {er[0..7], s[0..7]} shares one 64B line (K4 gathers er+s in ONE line).
// s-columns are zeroed by k_node and accumulated by k_bucket_sum via global atomicAdd.
static constexpr size_t WS_AT      = 0;                        // 4096
static constexpr size_t WS_EE      = 4096;                     // 64
static constexpr size_t WS_EL      = 4160;                     // NN*8
static constexpr size_t WS_ERS     = WS_EL + (size_t)NN * 8;   // NN*16 (64B-aligned)
static constexpr size_t WS_CCNT    = WS_ERS + (size_t)NN * 16; // NB
static constexpr size_t WS_PART    = WS_CCNT + NB + 2;         // NB*CAPB u32

// K1a: At[c][i] = sum_o W_fc[i, h*64+o]*attn[h,o]; c<8->attn_l, c>=8->attn_r. Zeroes ccnt.
__global__ __launch_bounds__(256) void k_prep_A(const float* __restrict__ W_fc,
                                                const float* __restrict__ attn_l,
                                                const float* __restrict__ attn_r,
                                                float* __restrict__ At,
                                                unsigned* __restrict__ ccnt) {
    int t = blockIdx.x * 256 + threadIdx.x;   // 0..4095
    if (t < NB) ccnt[t] = 0u;
    int c = t >> 8;
    int i = t & 255;
    int h = c & 7;
    const float* attn = (c < 8) ? attn_l : attn_r;
    const float* wrow = W_fc + (size_t)i * (NH * OF) + h * OF;
    const float* arow = attn + h * OF;
    float acc = 0.f;
#pragma unroll 8
    for (int o = 0; o < OF; ++o) acc += wrow[o] * arow[o];
    At[c * INF_ + i] = acc;
}

// K1b: ee_tab[t][h]
__global__ __launch_bounds__(512) void k_prep_ee(const float* __restrict__ edge_emb,
                                                 const float* __restrict__ W_e,
                                                 const float* __restrict__ attn_e,
                                                 float* __restrict__ ee_tab) {
    __shared__ float B[EF][NH];
    int t = threadIdx.x;
    int g = t >> 3, h = t & 7;
    const float* wrow = W_e + (size_t)g * (NH * EF) + h * EF;
    const float* arow = attn_e + h * EF;
    float acc = 0.f;
#pragma unroll 8
    for (int f = 0; f < EF; ++f) acc += wrow[f] * arow[f];
    B[g][h] = acc;
    __syncthreads();
    if (t < NT * NH) {
        int tt = t >> 3, hh = t & 7;
        float a = 0.f;
#pragma unroll 8
        for (int g2 = 0; g2 < EF; ++g2) a += edge_emb[tt * EF + g2] * B[g2][hh];
        ee_tab[tt * NH + hh] = a;
    }
}

// K2: el[n][h], ers[n][0..7]=er, ers[n][8..15]=0 (s accumulator init)
__global__ __launch_bounds__(256) void k_node(const float* __restrict__ feat,
                                              const float* __restrict__ At,
                                              float* __restrict__ el,
                                              float* __restrict__ ers) {
    int n = blockIdx.x * 256 + threadIdx.x;
    if (n >= NN) return;
    const float4* f4 = (const float4*)(feat + (size_t)n * INF_);
    const float4* A4 = (const float4*)At;
    float acc[16];
#pragma unroll
    for (int c = 0; c < 16; ++c) acc[c] = 0.f;
    for (int iq = 0; iq < INF_ / 4; ++iq) {
        float4 f = f4[iq];
#pragma unroll
        for (int c = 0; c < 16; ++c) {
            float4 a = A4[c * 64 + iq];
            acc[c] += f.x * a.x + f.y * a.y + f.z * a.z + f.w * a.w;
        }
    }
    float4* e4 = (float4*)(el + (size_t)n * 8);
    e4[0] = make_float4(acc[0], acc[1], acc[2], acc[3]);
    e4[1] = make_float4(acc[4], acc[5], acc[6], acc[7]);
    float4* r4 = (float4*)(ers + (size_t)n * 16);
    r4[0] = make_float4(acc[8], acc[9], acc[10], acc[11]);
    r4[1] = make_float4(acc[12], acc[13], acc[14], acc[15]);
    r4[2] = make_float4(0.f, 0.f, 0.f, 0.f);
    r4[3] = make_float4(0.f, 0.f, 0.f, 0.f);
}

// K3a: partition into NB buckets. recs cached in VGPRs (src/dst/etype read once).
__global__ __launch_bounds__(256) void k_partition(const int* __restrict__ src,
                                                   const int* __restrict__ dst,
                                                   const int* __restrict__ etype,
                                                   unsigned* __restrict__ ccnt,
                                                   unsigned* __restrict__ part) {
    __shared__ unsigned hist[NB];
    __shared__ unsigned cursor[NB];
    int tid = threadIdx.x;
    size_t base = (size_t)blockIdx.x * EPB;
    unsigned long long rc[16];
    for (int i = tid; i < NB; i += 256) hist[i] = 0u;
    __syncthreads();
#pragma unroll
    for (int k = 0; k < 16; ++k) {
        size_t j = base + (size_t)k * 256 + tid;
        if (j < NE) {
            int dj = dst[j];
            rc[k] = (unsigned long long)(unsigned)src[j]
                  | ((unsigned long long)(unsigned)etype[j] << 17)
                  | ((unsigned long long)(unsigned)dj << 20);
            atomicAdd(&hist[dj >> BSH], 1u);
        } else rc[k] = ~0ull;
    }
    __syncthreads();
    for (int i = tid; i < NB; i += 256) {
        unsigned h = hist[i];
        cursor[i] = h ? atomicAdd(ccnt + i, h) : 0u;
    }
    __syncthreads();
#pragma unroll
    for (int k = 0; k < 16; ++k) {
        if (rc[k] == ~0ull) continue;
        int dj = (int)(rc[k] >> 20);
        int b = dj >> BSH;
        unsigned pos = atomicAdd(&cursor[b], 1u);
        if (pos < CAPB)
            part[(size_t)b * CAPB + pos] =
                (unsigned)(rc[k] & 0xFFFFFull) | ((unsigned)(dj & (BNODES - 1)) << 20);
    }
}

// K3b: per-sub-bucket sum. lane=(edge_sub,head).
// Slot assignment is INTERLEAVED: sub-block c owns slots {k*128 + c*32 + e_sub} so all
// 4 sub-blocks get exactly ceil(cnt/4) work (no ragged chunk tail), and each still
// touches distinct 128B lines of part.
// Main loop is 8-wide: 8 pp loads issued, then 8 dependent el gathers, then 8
// compute+LDS-atomic. Counted vmcnt pipelines the 16 loads; serial exposure per
// iteration ~= 1 rec latency + 1 gather latency for 64 edges/wave-iter.
__global__ __launch_bounds__(256) void k_bucket_sum(const unsigned* __restrict__ part,
                                                    const unsigned* __restrict__ ccnt,
                                                    const float* __restrict__ el,
                                                    const float* __restrict__ ers,
                                                    const float* __restrict__ ee_tab,
                                                    float* __restrict__ ers_out) {
    __shared__ float sbin[BNODES * 9];
    __shared__ float er_l[BNODES * 9];
    __shared__ float ee_l[NT * NH];
    int bs = blockIdx.x;
    int b = bs >> 2, c = bs & 3;     // SPLIT=4
    int tid = threadIdx.x;
    int e_sub = tid >> 3, h = tid & 7;   // e_sub in 0..31
    int n0 = b << BSH;
    int nn = NN - n0; if (nn > BNODES) nn = BNODES;

    for (int i = tid; i < BNODES * 9; i += 256) sbin[i] = 0.f;
    if (tid < NT * NH) ee_l[tid] = ee_tab[tid];
    for (int i = tid; i < nn * NH; i += 256) {
        int nl = i >> 3, hh = i & 7;
        er_l[nl * 9 + hh] = ers[(size_t)(n0 + nl) * 16 + hh];
    }
    __syncthreads();

    unsigned cnt = ccnt[b]; if (cnt > CAPB) cnt = CAPB;
    const unsigned* pp = part + (size_t)b * CAPB;
    unsigned e = (unsigned)(c * 32 + e_sub);
    // main loop: 8 edges per lane per iteration, slot stride 128
    for (; e + 896 < cnt; e += 1024) {
        unsigned r0 = pp[e];
        unsigned r1 = pp[e + 128];
        unsigned r2 = pp[e + 256];
        unsigned r3 = pp[e + 384];
        unsigned r4 = pp[e + 512];
        unsigned r5 = pp[e + 640];
        unsigned r6 = pp[e + 768];
        unsigned r7 = pp[e + 896];
        float l0 = el[(size_t)(r0 & 0x1FFFFu) * 8 + h];
        float l1 = el[(size_t)(r1 & 0x1FFFFu) * 8 + h];
        float l2 = el[(size_t)(r2 & 0x1FFFFu) * 8 + h];
        float l3 = el[(size_t)(r3 & 0x1FFFFu) * 8 + h];
        float l4 = el[(size_t)(r4 & 0x1FFFFu) * 8 + h];
        float l5 = el[(size_t)(r5 & 0x1FFFFu) * 8 + h];
        float l6 = el[(size_t)(r6 & 0x1FFFFu) * 8 + h];
        float l7 = el[(size_t)(r7 & 0x1FFFFu) * 8 + h];
#define DO_EDGE(rr, ll)                                                        \
        {                                                                      \
            int et = (int)(((rr) >> 17) & 7u);                                 \
            int dl = (int)(((rr) >> 20) & (BNODES - 1));                       \
            float v = (ll) + er_l[dl * 9 + h] + ee_l[et * NH + h];             \
            atomicAdd(&sbin[dl * 9 + h], __expf(fmaxf(v, 0.f)));               \
        }
        DO_EDGE(r0, l0)
        DO_EDGE(r1, l1)
        DO_EDGE(r2, l2)
        DO_EDGE(r3, l3)
        DO_EDGE(r4, l4)
        DO_EDGE(r5, l5)
        DO_EDGE(r6, l6)
        DO_EDGE(r7, l7)
    }
    // tail: single edge per lane per iteration
    for (; e < cnt; e += 128) {
        unsigned rec = pp[e];
        float lv = el[(size_t)(rec & 0x1FFFFu) * 8 + h];
        DO_EDGE(rec, lv)
    }
#undef DO_EDGE
    __syncthreads();
    for (int i = tid; i < nn * NH; i += 256) {
        int nl = i >> 3, hh = i & 7;
        atomicAdd(&ers_out[(size_t)(n0 + nl) * 16 + 8 + hh], sbin[nl * 9 + hh]);
    }
}

// K4: out[j][h] = exp(e)/s. Gathers exactly 2 lines/edge: el[sj] (32B in 3.2MB table),
// ers[dj] (er+s in one 64B line). __expf matches k_bucket_sum's exp so the ratio is exact.
__global__ __launch_bounds__(256) void k_edge_out(const int* __restrict__ src,
                                                  const int* __restrict__ dst,
                                                  const int* __restrict__ etype,
                                                  const float* __restrict__ el,
                                                  const float* __restrict__ ers,
                                                  const float* __restrict__ ee_tab,
                                                  float* __restrict__ out) {
    int j = blockIdx.x * 256 + threadIdx.x;
    if (j >= NE) return;
    int sj = src[j], dj = dst[j], tj = etype[j];
    const float4* el4 = (const float4*)(el + (size_t)sj * 8);
    const float4* E   = (const float4*)(ers + (size_t)dj * 16);
    const float4* ee4 = (const float4*)(ee_tab + tj * NH);
    float4 l0 = el4[0], l1 = el4[1];
    float4 r0 = E[0], r1 = E[1];
    float4 s0 = E[2], s1 = E[3];
    float4 e0 = ee4[0], e1 = ee4[1];
    float4 o0, o1;
    o0.x = __expf(fmaxf(l0.x + r0.x + e0.x, 0.f)) / s0.x;
    o0.y = __expf(fmaxf(l0.y + r0.y + e0.y, 0.f)) / s0.y;
    o0.z = __expf(fmaxf(l0.z + r0.z + e0.z, 0.f)) / s0.z;
    o0.w = __expf(fmaxf(l0.w + r0.w + e0.w, 0.f)) / s0.w;
    o1.x = __expf(fmaxf(l1.x + r1.x + e1.x, 0.f)) / s1.x;
    o1.y = __expf(fmaxf(l1.y + r1.y + e1.y, 0.f)) / s1.y;
    o1.z = __expf(fmaxf(l1.z + r1.z + e1.z, 0.f)) / s1.z;
    o1.w = __expf(fmaxf(l1.w + r1.w + e1.w, 0.f)) / s1.w;
    float4* o4 = (float4*)(out + (size_t)j * NH);
    o4[0] = o0;
    o4[1] = o1;
}

extern "C" void kernel_launch(void* const* d_in, const int* in_sizes, int n_in,
                              void* d_out, int out_size, void* d_ws, size_t ws_size,
                              hipStream_t stream) {
    const float* feat     = (const float*)d_in[0];
    const int*   etype    = (const int*)d_in[1];
    const int*   src      = (const int*)d_in[2];
    const int*   dst      = (const int*)d_in[3];
    const float* W_fc     = (const float*)d_in[4];
    const float* edge_emb = (const float*)d_in[5];
    const float* W_e      = (const float*)d_in[6];
    const float* attn_l   = (const float*)d_in[7];
    const float* attn_r   = (const float*)d_in[8];
    const float* attn_e   = (const float*)d_in[9];

    float*    ws      = (float*)d_ws;
    float*    At      = ws + WS_AT;
    float*    ee_tab  = ws + WS_EE;
    float*    el      = ws + WS_EL;
    float*    ers     = ws + WS_ERS;
    unsigned* ccnt    = (unsigned*)(ws + WS_CCNT);
    unsigned* part    = (unsigned*)(ws + WS_PART);
    float*    out     = (float*)d_out;

    hipLaunchKernelGGL(k_prep_A, dim3(16), dim3(256), 0, stream, W_fc, attn_l, attn_r, At, ccnt);
    hipLaunchKernelGGL(k_prep_ee, dim3(1), dim3(512), 0, stream, edge_emb, W_e, attn_e, ee_tab);
    hipLaunchKernelGGL(k_node, dim3((NN + 255) / 256), dim3(256), 0, stream, feat, At, el, ers);
    hipLaunchKernelGGL(k_partition, dim3((NE + EPB - 1) / EPB), dim3(256), 0, stream,
                       src, dst, etype, ccnt, part);
    hipLaunchKernelGGL(k_bucket_sum, dim3(NB * SPLIT), dim3(256), 0, stream,
                       part, ccnt, el, ers, ee_tab, ers);
    hipLaunchKernelGGL(k_edge_out, dim3((NE + 255) / 256), dim3(256), 0, stream,
                       src, dst, etype, el, ers, ee_tab, out);
}

// Round 4
// 519.551 us; speedup vs baseline: 1.0726x; 1.0084x over previous
//
#include <hip/hip_runtime.h>
#include <math.h>

#define NN 100000
#define NE 3200000
#define INF_ 256
#define NH 8
#define OF 64
#define EF 64
#define NT 8

#define BSH 7                  // log2(nodes per bucket)
#define BNODES 128             // nodes per bucket
#define NB 782                 // ceil(NN/128)
#define CAPB 4608              // slots/bucket: Poisson(4096)+8 sigma
#define SPLIT 4                // sub-blocks per bucket in k_bucket_sum
#define EPB 4096               // edges per k_partition block

// ws layout (float units). el separated from ers so the 3.2MB el table fits per-XCD L2;
// ers[n] = {er[0..7], s[0..7]} shares one 64B line (K4 gathers er+s in ONE line).
// s-columns are zeroed by k_node and accumulated by k_bucket_sum via global atomicAdd.
static constexpr size_t WS_AT      = 0;                        // 4096
static constexpr size_t WS_EE      = 4096;                     // 64
static constexpr size_t WS_EL      = 4160;                     // NN*8
static constexpr size_t WS_ERS     = WS_EL + (size_t)NN * 8;   // NN*16 (64B-aligned)
static constexpr size_t WS_CCNT    = WS_ERS + (size_t)NN * 16; // NB
static constexpr size_t WS_PART    = WS_CCNT + NB + 2;         // NB*CAPB u32

// K1a: At[c][i] = sum_o W_fc[i, h*64+o]*attn[h,o]; c<8->attn_l, c>=8->attn_r. Zeroes ccnt.
__global__ __launch_bounds__(256) void k_prep_A(const float* __restrict__ W_fc,
                                                const float* __restrict__ attn_l,
                                                const float* __restrict__ attn_r,
                                                float* __restrict__ At,
                                                unsigned* __restrict__ ccnt) {
    int t = blockIdx.x * 256 + threadIdx.x;   // 0..4095
    if (t < NB) ccnt[t] = 0u;
    int c = t >> 8;
    int i = t & 255;
    int h = c & 7;
    const float* attn = (c < 8) ? attn_l : attn_r;
    const float* wrow = W_fc + (size_t)i * (NH * OF) + h * OF;
    const float* arow = attn + h * OF;
    float acc = 0.f;
#pragma unroll 8
    for (int o = 0; o < OF; ++o) acc += wrow[o] * arow[o];
    At[c * INF_ + i] = acc;
}

// K1b: ee_tab[t][h]
__global__ __launch_bounds__(512) void k_prep_ee(const float* __restrict__ edge_emb,
                                                 const float* __restrict__ W_e,
                                                 const float* __restrict__ attn_e,
                                                 float* __restrict__ ee_tab) {
    __shared__ float B[EF][NH];
    int t = threadIdx.x;
    int g = t >> 3, h = t & 7;
    const float* wrow = W_e + (size_t)g * (NH * EF) + h * EF;
    const float* arow = attn_e + h * EF;
    float acc = 0.f;
#pragma unroll 8
    for (int f = 0; f < EF; ++f) acc += wrow[f] * arow[f];
    B[g][h] = acc;
    __syncthreads();
    if (t < NT * NH) {
        int tt = t >> 3, hh = t & 7;
        float a = 0.f;
#pragma unroll 8
        for (int g2 = 0; g2 < EF; ++g2) a += edge_emb[tt * EF + g2] * B[g2][hh];
        ee_tab[tt * NH + hh] = a;
    }
}

// K2: el[n][h], ers[n][0..7]=er, ers[n][8..15]=0 (s accumulator init)
__global__ __launch_bounds__(256) void k_node(const float* __restrict__ feat,
                                              const float* __restrict__ At,
                                              float* __restrict__ el,
                                              float* __restrict__ ers) {
    int n = blockIdx.x * 256 + threadIdx.x;
    if (n >= NN) return;
    const float4* f4 = (const float4*)(feat + (size_t)n * INF_);
    const float4* A4 = (const float4*)At;
    float acc[16];
#pragma unroll
    for (int c = 0; c < 16; ++c) acc[c] = 0.f;
    for (int iq = 0; iq < INF_ / 4; ++iq) {
        float4 f = f4[iq];
#pragma unroll
        for (int c = 0; c < 16; ++c) {
            float4 a = A4[c * 64 + iq];
            acc[c] += f.x * a.x + f.y * a.y + f.z * a.z + f.w * a.w;
        }
    }
    float4* e4 = (float4*)(el + (size_t)n * 8);
    e4[0] = make_float4(acc[0], acc[1], acc[2], acc[3]);
    e4[1] = make_float4(acc[4], acc[5], acc[6], acc[7]);
    float4* r4 = (float4*)(ers + (size_t)n * 16);
    r4[0] = make_float4(acc[8], acc[9], acc[10], acc[11]);
    r4[1] = make_float4(acc[12], acc[13], acc[14], acc[15]);
    r4[2] = make_float4(0.f, 0.f, 0.f, 0.f);
    r4[3] = make_float4(0.f, 0.f, 0.f, 0.f);
}

// K3a: partition into NB buckets. recs cached in VGPRs (src/dst/etype read once).
__global__ __launch_bounds__(256) void k_partition(const int* __restrict__ src,
                                                   const int* __restrict__ dst,
                                                   const int* __restrict__ etype,
                                                   unsigned* __restrict__ ccnt,
                                                   unsigned* __restrict__ part) {
    __shared__ unsigned hist[NB];
    __shared__ unsigned cursor[NB];
    int tid = threadIdx.x;
    size_t base = (size_t)blockIdx.x * EPB;
    unsigned long long rc[16];
    for (int i = tid; i < NB; i += 256) hist[i] = 0u;
    __syncthreads();
#pragma unroll
    for (int k = 0; k < 16; ++k) {
        size_t j = base + (size_t)k * 256 + tid;
        if (j < NE) {
            int dj = dst[j];
            rc[k] = (unsigned long long)(unsigned)src[j]
                  | ((unsigned long long)(unsigned)etype[j] << 17)
                  | ((unsigned long long)(unsigned)dj << 20);
            atomicAdd(&hist[dj >> BSH], 1u);
        } else rc[k] = ~0ull;
    }
    __syncthreads();
    for (int i = tid; i < NB; i += 256) {
        unsigned h = hist[i];
        cursor[i] = h ? atomicAdd(ccnt + i, h) : 0u;
    }
    __syncthreads();
#pragma unroll
    for (int k = 0; k < 16; ++k) {
        if (rc[k] == ~0ull) continue;
        int dj = (int)(rc[k] >> 20);
        int b = dj >> BSH;
        unsigned pos = atomicAdd(&cursor[b], 1u);
        if (pos < CAPB)
            part[(size_t)b * CAPB + pos] =
                (unsigned)(rc[k] & 0xFFFFFull) | ((unsigned)(dj & (BNODES - 1)) << 20);
    }
}

// K3b: per-sub-bucket sum — LANE-PER-EDGE layout.
// Each lane owns one edge: coalesced rec load (64 consecutive slots/wave), then
// independent float4 gathers of el[sj] (random, L2), ers[dj] (4KB/block working set ->
// L1-hot; er_l staging deleted), ee_tab[et] (256B, L1-hot). One gather instruction
// now puts up to 64 distinct lines in flight per wave (vs 8 in the (e_sub,h) layout)
// -> per-CU outstanding-miss parallelism up ~10-30x. 8 exps + 8 ds_add_f32 per lane.
// sbin keeps the *9 pad: bank(9*dl+h) is a permutation of dl -> conflict-free modulo
// duplicate-dl serialization. Sub-block c owns slots {k*1024 + c*256 + tid}: balanced
// to within one 256-slot granule, coalesced within each wave.
__global__ __launch_bounds__(256) void k_bucket_sum(const unsigned* __restrict__ part,
                                                    const unsigned* __restrict__ ccnt,
                                                    const float* __restrict__ el,
                                                    const float* __restrict__ ers,
                                                    const float* __restrict__ ee_tab,
                                                    float* __restrict__ ers_out) {
    __shared__ float sbin[BNODES * 9];
    int bs = blockIdx.x;
    int b = bs >> 2, c = bs & 3;     // SPLIT=4
    int tid = threadIdx.x;
    int n0 = b << BSH;
    int nn = NN - n0; if (nn > BNODES) nn = BNODES;

    for (int i = tid; i < BNODES * 9; i += 256) sbin[i] = 0.f;
    __syncthreads();

    unsigned cnt = ccnt[b]; if (cnt > CAPB) cnt = CAPB;
    const unsigned* pp = part + (size_t)b * CAPB;
    for (unsigned e = (unsigned)(c * 256 + tid); e < cnt; e += 1024) {
        unsigned rec = pp[e];
        int sj = (int)(rec & 0x1FFFFu);
        int et = (int)((rec >> 17) & 7u);
        int dl = (int)((rec >> 20) & (BNODES - 1));
        const float4* el4 = (const float4*)(el + (size_t)sj * 8);
        const float4* E   = (const float4*)(ers + (size_t)(n0 + dl) * 16);
        const float4* ee4 = (const float4*)(ee_tab + et * NH);
        float4 la = el4[0], lb = el4[1];
        float4 ra = E[0],   rb = E[1];
        float4 ea = ee4[0], eb = ee4[1];
        float* sb = &sbin[dl * 9];
        atomicAdd(&sb[0], __expf(fmaxf(la.x + ra.x + ea.x, 0.f)));
        atomicAdd(&sb[1], __expf(fmaxf(la.y + ra.y + ea.y, 0.f)));
        atomicAdd(&sb[2], __expf(fmaxf(la.z + ra.z + ea.z, 0.f)));
        atomicAdd(&sb[3], __expf(fmaxf(la.w + ra.w + ea.w, 0.f)));
        atomicAdd(&sb[4], __expf(fmaxf(lb.x + rb.x + eb.x, 0.f)));
        atomicAdd(&sb[5], __expf(fmaxf(lb.y + rb.y + eb.y, 0.f)));
        atomicAdd(&sb[6], __expf(fmaxf(lb.z + rb.z + eb.z, 0.f)));
        atomicAdd(&sb[7], __expf(fmaxf(lb.w + rb.w + eb.w, 0.f)));
    }
    __syncthreads();
    for (int i = tid; i < nn * NH; i += 256) {
        int nl = i >> 3, hh = i & 7;
        atomicAdd(&ers_out[(size_t)(n0 + nl) * 16 + 8 + hh], sbin[nl * 9 + hh]);
    }
}

// K4: out[j][h] = exp(e)/s. Gathers exactly 2 lines/edge: el[sj] (32B in 3.2MB table),
// ers[dj] (er+s in one 64B line). __expf matches k_bucket_sum's exp so the ratio is exact.
__global__ __launch_bounds__(256) void k_edge_out(const int* __restrict__ src,
                                                  const int* __restrict__ dst,
                                                  const int* __restrict__ etype,
                                                  const float* __restrict__ el,
                                                  const float* __restrict__ ers,
                                                  const float* __restrict__ ee_tab,
                                                  float* __restrict__ out) {
    int j = blockIdx.x * 256 + threadIdx.x;
    if (j >= NE) return;
    int sj = src[j], dj = dst[j], tj = etype[j];
    const float4* el4 = (const float4*)(el + (size_t)sj * 8);
    const float4* E   = (const float4*)(ers + (size_t)dj * 16);
    const float4* ee4 = (const float4*)(ee_tab + tj * NH);
    float4 l0 = el4[0], l1 = el4[1];
    float4 r0 = E[0], r1 = E[1];
    float4 s0 = E[2], s1 = E[3];
    float4 e0 = ee4[0], e1 = ee4[1];
    float4 o0, o1;
    o0.x = __expf(fmaxf(l0.x + r0.x + e0.x, 0.f)) / s0.x;
    o0.y = __expf(fmaxf(l0.y + r0.y + e0.y, 0.f)) / s0.y;
    o0.z = __expf(fmaxf(l0.z + r0.z + e0.z, 0.f)) / s0.z;
    o0.w = __expf(fmaxf(l0.w + r0.w + e0.w, 0.f)) / s0.w;
    o1.x = __expf(fmaxf(l1.x + r1.x + e1.x, 0.f)) / s1.x;
    o1.y = __expf(fmaxf(l1.y + r1.y + e1.y, 0.f)) / s1.y;
    o1.z = __expf(fmaxf(l1.z + r1.z + e1.z, 0.f)) / s1.z;
    o1.w = __expf(fmaxf(l1.w + r1.w + e1.w, 0.f)) / s1.w;
    float4* o4 = (float4*)(out + (size_t)j * NH);
    o4[0] = o0;
    o4[1] = o1;
}

extern "C" void kernel_launch(void* const* d_in, const int* in_sizes, int n_in,
                              void* d_out, int out_size, void* d_ws, size_t ws_size,
                              hipStream_t stream) {
    const float* feat     = (const float*)d_in[0];
    const int*   etype    = (const int*)d_in[1];
    const int*   src      = (const int*)d_in[2];
    const int*   dst      = (const int*)d_in[3];
    const float* W_fc     = (const float*)d_in[4];
    const float* edge_emb = (const float*)d_in[5];
    const float* W_e      = (const float*)d_in[6];
    const float* attn_l   = (const float*)d_in[7];
    const float* attn_r   = (const float*)d_in[8];
    const float* attn_e   = (const float*)d_in[9];

    float*    ws      = (float*)d_ws;
    float*    At      = ws + WS_AT;
    float*    ee_tab  = ws + WS_EE;
    float*    el      = ws + WS_EL;
    float*    ers     = ws + WS_ERS;
    unsigned* ccnt    = (unsigned*)(ws + WS_CCNT);
    unsigned* part    = (unsigned*)(ws + WS_PART);
    float*    out     = (float*)d_out;

    hipLaunchKernelGGL(k_prep_A, dim3(16), dim3(256), 0, stream, W_fc, attn_l, attn_r, At, ccnt);
    hipLaunchKernelGGL(k_prep_ee, dim3(1), dim3(512), 0, stream, edge_emb, W_e, attn_e, ee_tab);
    hipLaunchKernelGGL(k_node, dim3((NN + 255) / 256), dim3(256), 0, stream, feat, At, el, ers);
    hipLaunchKernelGGL(k_partition, dim3((NE + EPB - 1) / EPB), dim3(256), 0, stream,
                       src, dst, etype, ccnt, part);
    hipLaunchKernelGGL(k_bucket_sum, dim3(NB * SPLIT), dim3(256), 0, stream,
                       part, ccnt, el, ers, ee_tab, ers);
    hipLaunchKernelGGL(k_edge_out, dim3((NE + 255) / 256), dim3(256), 0, stream,
                       src, dst, etype, el, ers, ee_tab, out);
}